// Round 1
// baseline (4391.798 us; speedup 1.0000x reference)
//
#include <hip/hip_runtime.h>

#define NROWS_TOTAL 65536
#define DDIM 512
#define KCODES 1024
#define LLEV 4

#define ROWS 32      // rows per workgroup
#define KT 512       // k per k-tile (2 tiles)
#define DC 16        // d per staged chunk (32 chunks)
#define RSTRIDE 20   // resid tile row stride in floats (16B-aligned rows)

// ---------------- kernel 1: codebook squared norms -> d_ws ----------------
__global__ void csq_kernel(const float* __restrict__ cb, float* __restrict__ csq) {
  int row  = blockIdx.x * 4 + (threadIdx.x >> 6);   // 4096 rows, one per wave
  int lane = threadIdx.x & 63;
  const float* p = cb + (size_t)row * DDIM;
  float s = 0.f;
#pragma unroll
  for (int i = 0; i < 8; ++i) { float v = p[lane + 64 * i]; s = fmaf(v, v, s); }
#pragma unroll
  for (int off = 32; off > 0; off >>= 1) s += __shfl_down(s, off, 64);
  if (lane == 0) csq[row] = s;
}

// ---------------- kernel 2: fused residual quantization ----------------
__launch_bounds__(256, 2)
__global__ void rq_kernel(const float* __restrict__ x, const float* __restrict__ cb,
                          const float* __restrict__ csq, float* __restrict__ out) {
  __shared__ float ls_cbT[DC * KT];       // [d][k] transposed tile, 32 KB
  __shared__ float ls_r[ROWS * RSTRIDE];  // resid tile for current d-chunk
  __shared__ float ls_minv[ROWS * 64];
  __shared__ int   ls_mini[ROWS * 64];
  __shared__ float ls_rsqp[ROWS * 8];
  __shared__ float ls_rsq[ROWS];
  __shared__ int   ls_idx[ROWS];

  const int tid = threadIdx.x;
  const int rg  = tid >> 6;          // wave id = row group (4 waves x 8 rows)
  const int kg  = tid & 63;
  const int own_row = tid >> 3;      // residual ownership: 32 rows x 8 threads
  const int own_d0  = (tid & 7) * 64;
  const int rowbase = blockIdx.x * ROWS;

  // residual lives in registers: 64 floats per thread
  float rres[64];
  {
    const float4* xp = (const float4*)(x + (size_t)(rowbase + own_row) * DDIM + own_d0);
#pragma unroll
    for (int i = 0; i < 16; ++i) {
      float4 v = xp[i];
      rres[4*i] = v.x; rres[4*i+1] = v.y; rres[4*i+2] = v.z; rres[4*i+3] = v.w;
    }
  }

  for (int l = 0; l < LLEV; ++l) {
    // ---- r_sq (deterministic two-stage reduce) ----
    {
      float p = 0.f;
#pragma unroll
      for (int i = 0; i < 64; ++i) p = fmaf(rres[i], rres[i], p);
      ls_rsqp[own_row * 8 + (tid & 7)] = p;
    }
    __syncthreads();
    if (tid < ROWS) {
      float s = 0.f;
#pragma unroll
      for (int i = 0; i < 8; ++i) s += ls_rsqp[tid * 8 + i];
      ls_rsq[tid] = s;
    }

    float mv[8]; int mi[8];
#pragma unroll
    for (int r = 0; r < 8; ++r) { mv[r] = 3.4e38f; mi[r] = 0; }

    const float* cbl = cb + (size_t)l * KCODES * DDIM;

    for (int kt = 0; kt < KCODES / KT; ++kt) {
      float acc[8][8];
#pragma unroll
      for (int r = 0; r < 8; ++r)
#pragma unroll
        for (int c = 0; c < 8; ++c) acc[r][c] = 0.f;

      for (int dc = 0; dc < DDIM / DC; ++dc) {
        __syncthreads();  // previous chunk fully consumed (also publishes ls_rsq)
        // stage cbT[d][k] (transpose during staging; global reads 64B-coalesced)
        {
          int krow = tid >> 2;          // 0..63
          int dcol = (tid & 3) * 4;     // 0,4,8,12
#pragma unroll
          for (int p = 0; p < 8; ++p) {
            int klocal = p * 64 + krow;
            float4 v = *(const float4*)(cbl + (size_t)(kt * KT + klocal) * DDIM + dc * DC + dcol);
            ls_cbT[(dcol + 0) * KT + klocal] = v.x;
            ls_cbT[(dcol + 1) * KT + klocal] = v.y;
            ls_cbT[(dcol + 2) * KT + klocal] = v.z;
            ls_cbT[(dcol + 3) * KT + klocal] = v.w;
          }
        }
        // stage resid tile for this d-chunk from owning registers
        if ((tid & 7) == (dc >> 2)) {
          int q = dc & 3;
#pragma unroll
          for (int i = 0; i < 4; ++i)
            *(float4*)&ls_r[own_row * RSTRIDE + i * 4] =
              make_float4(rres[q*16 + 4*i], rres[q*16 + 4*i + 1],
                          rres[q*16 + 4*i + 2], rres[q*16 + 4*i + 3]);
        }
        __syncthreads();
        // compute: 8 rows x 8 cols per thread over DC d's
        for (int ds4 = 0; ds4 < DC / 4; ++ds4) {
          float rvf[4][8];
#pragma unroll
          for (int r = 0; r < 8; ++r) {
            float4 t = *(const float4*)&ls_r[(rg * 8 + r) * RSTRIDE + ds4 * 4];
            rvf[0][r] = t.x; rvf[1][r] = t.y; rvf[2][r] = t.z; rvf[3][r] = t.w;
          }
#pragma unroll
          for (int j = 0; j < 4; ++j) {
            float4 cv0 = *(const float4*)&ls_cbT[(ds4 * 4 + j) * KT + 4 * kg];
            float4 cv1 = *(const float4*)&ls_cbT[(ds4 * 4 + j) * KT + KT / 2 + 4 * kg];
#pragma unroll
            for (int r = 0; r < 8; ++r) {
              float rv = rvf[j][r];
              acc[r][0] = fmaf(rv, cv0.x, acc[r][0]);
              acc[r][1] = fmaf(rv, cv0.y, acc[r][1]);
              acc[r][2] = fmaf(rv, cv0.z, acc[r][2]);
              acc[r][3] = fmaf(rv, cv0.w, acc[r][3]);
              acc[r][4] = fmaf(rv, cv1.x, acc[r][4]);
              acc[r][5] = fmaf(rv, cv1.y, acc[r][5]);
              acc[r][6] = fmaf(rv, cv1.z, acc[r][6]);
              acc[r][7] = fmaf(rv, cv1.w, acc[r][7]);
            }
          }
        }
      }
      // scores + running argmin (exact np formula: (r_sq + c_sq) - 2*dot, T=1)
#pragma unroll
      for (int g = 0; g < 2; ++g)
#pragma unroll
        for (int c = 0; c < 4; ++c) {
          int k = kt * KT + g * (KT / 2) + 4 * kg + c;
          float cs = csq[l * KCODES + k];
#pragma unroll
          for (int r = 0; r < 8; ++r) {
            float s = (ls_rsq[rg * 8 + r] + cs) - 2.0f * acc[r][g * 4 + c];
            if (s < mv[r]) { mv[r] = s; mi[r] = k; }  // ascending-k scan: strict < = first-index ties
          }
        }
    }

    // ---- cross-thread argmin reduce ----
#pragma unroll
    for (int r = 0; r < 8; ++r) {
      ls_minv[(rg * 8 + r) * 64 + kg] = mv[r];
      ls_mini[(rg * 8 + r) * 64 + kg] = mi[r];
    }
    __syncthreads();
    if (tid < ROWS) {
      float bv = ls_minv[tid * 64]; int bi = ls_mini[tid * 64];
      for (int i = 1; i < 64; ++i) {
        float v = ls_minv[tid * 64 + i]; int ii = ls_mini[tid * 64 + i];
        if (v < bv || (v == bv && ii < bi)) { bv = v; bi = ii; }
      }
      ls_idx[tid] = bi;
      out[(size_t)NROWS_TOTAL * DDIM + (size_t)(rowbase + tid) * LLEV + l] = (float)bi;
    }
    __syncthreads();
    // ---- residual update: r -= cb[l][idx] ----
    {
      int idx = ls_idx[own_row];
      const float4* cp = (const float4*)(cbl + (size_t)idx * DDIM + own_d0);
#pragma unroll
      for (int i = 0; i < 16; ++i) {
        float4 v = cp[i];
        rres[4*i]   -= v.x; rres[4*i+1] -= v.y;
        rres[4*i+2] -= v.z; rres[4*i+3] -= v.w;
      }
    }
  }

  // ---- quant = input - residual_final ----
  {
    const float4* xp = (const float4*)(x + (size_t)(rowbase + own_row) * DDIM + own_d0);
    float4* op = (float4*)(out + (size_t)(rowbase + own_row) * DDIM + own_d0);
#pragma unroll
    for (int i = 0; i < 16; ++i) {
      float4 v = xp[i];
      op[i] = make_float4(v.x - rres[4*i],   v.y - rres[4*i+1],
                          v.z - rres[4*i+2], v.w - rres[4*i+3]);
    }
  }
}

extern "C" void kernel_launch(void* const* d_in, const int* in_sizes, int n_in,
                              void* d_out, int out_size, void* d_ws, size_t ws_size,
                              hipStream_t stream) {
  const float* x  = (const float*)d_in[0];   // [N, D] fp32
  const float* cb = (const float*)d_in[1];   // [L, K, D] fp32
  float* out = (float*)d_out;                // quant [N*D] then codes [N*L] (as float)
  float* csq = (float*)d_ws;                 // [L*K] codeword squared norms

  csq_kernel<<<dim3((LLEV * KCODES) / 4), dim3(256), 0, stream>>>(cb, csq);
  rq_kernel<<<dim3(NROWS_TOTAL / ROWS), dim3(256), 0, stream>>>(x, cb, csq, out);
}

// Round 2
// 4290.137 us; speedup vs baseline: 1.0237x; 1.0237x over previous
//
#include <hip/hip_runtime.h>

#define NROWS_TOTAL 65536
#define DDIM 512
#define KCODES 1024
#define LLEV 4
#define ROWS 32
#define KT 512
#define CODES_OFF ((size_t)NROWS_TOTAL * DDIM)

typedef __attribute__((address_space(1))) const unsigned int glb_u32_t;
typedef __attribute__((address_space(3))) unsigned int lds_u32_t;

__device__ __forceinline__ void gload_lds16(const float* g, float* l) {
  __builtin_amdgcn_global_load_lds((glb_u32_t*)g, (lds_u32_t*)l, 16, 0, 0);
}

// ---------------- codebook squared norms ----------------
__global__ void csq_kernel(const float* __restrict__ cb, float* __restrict__ csq) {
  int row  = blockIdx.x * 4 + (threadIdx.x >> 6);
  int lane = threadIdx.x & 63;
  const float* p = cb + (size_t)row * DDIM;
  float s = 0.f;
#pragma unroll
  for (int i = 0; i < 8; ++i) { float v = p[lane + 64 * i]; s = fmaf(v, v, s); }
#pragma unroll
  for (int off = 32; off > 0; off >>= 1) s += __shfl_down(s, off, 64);
  if (lane == 0) csq[row] = s;
}

// ---------------- codebook transpose: cbT[l][d][k] ----------------
__global__ void transpose_kernel(const float* __restrict__ cb, float* __restrict__ cbT) {
  __shared__ float t[64][65];
  int l  = blockIdx.z;
  int kb = blockIdx.x * 64;
  int db = blockIdx.y * 64;
  int tid = threadIdx.x;
  {
    int kr = tid >> 2, dq = (tid & 3) * 16;
    const float* src = cb + ((size_t)(l * KCODES + kb + kr) * DDIM) + db + dq;
#pragma unroll
    for (int i = 0; i < 4; ++i) {
      float4 v = *(const float4*)(src + 4 * i);
      t[kr][dq + 4 * i + 0] = v.x; t[kr][dq + 4 * i + 1] = v.y;
      t[kr][dq + 4 * i + 2] = v.z; t[kr][dq + 4 * i + 3] = v.w;
    }
  }
  __syncthreads();
  {
    int dr = tid >> 2, kq = (tid & 3) * 16;
    float* dst = cbT + ((size_t)(l * DDIM + db + dr) * KCODES) + kb + kq;
#pragma unroll
    for (int i = 0; i < 4; ++i) {
      float4 v = make_float4(t[kq + 4 * i + 0][dr], t[kq + 4 * i + 1][dr],
                             t[kq + 4 * i + 2][dr], t[kq + 4 * i + 3][dr]);
      *(float4*)(dst + 4 * i) = v;
    }
  }
}

// ---------------- fast path: DMA-staged, single-barrier pipeline ----------------
__launch_bounds__(256, 2)
__global__ void rq_fast(const float* __restrict__ x, const float* __restrict__ cb,
                        const float* __restrict__ csq, const float* __restrict__ cbT,
                        float* __restrict__ out) {
  __shared__ float ls_cb[2][8 * KT];     // 2 x 16 KB, chunk = 8 d-rows x 512 k
  __shared__ float ls_r[2][ROWS * 12];   // staged residual d-chunk (8 + pad)
  __shared__ float ls_rsqp[ROWS * 8];
  __shared__ float ls_rsq[ROWS];

  const int tid = threadIdx.x;
  const int rg  = tid >> 6;
  const int kg  = tid & 63;
  const int own_row = tid >> 3;
  const int own_d0  = (tid & 7) * 64;
  const int rowbase = blockIdx.x * ROWS;

  float rres[64];
  {
    const float4* xp = (const float4*)(x + (size_t)(rowbase + own_row) * DDIM + own_d0);
#pragma unroll
    for (int i = 0; i < 16; ++i) {
      float4 v = xp[i];
      rres[4*i] = v.x; rres[4*i+1] = v.y; rres[4*i+2] = v.z; rres[4*i+3] = v.w;
    }
  }

  // issue chunk (l, j) into buffer buf.  j in [0,128): kt = j>>6, dc = j&63.
  auto issue_chunk = [&](int l, int j, int buf) {
    int kt = j >> 6, dc = j & 63;
    const float* gbase = cbT + ((size_t)(l * DDIM + dc * 8) * KCODES) + kt * KT + kg * 4;
    float* lbase = &ls_cb[buf][kg * 4];
#pragma unroll
    for (int s = 0; s < 4; ++s) {
      int dloc = rg * 2 + (s >> 1);
      int half = s & 1;
      gload_lds16(gbase + (size_t)dloc * KCODES + half * 256,
                  lbase + dloc * KT + half * 256);
    }
  };

#define WRQ(PAR, Q)                                                              \
  {                                                                              \
    float* dp = &ls_r[PAR][own_row * 12];                                        \
    *(float4*)(dp + 0) = make_float4(rres[(Q)*8+0], rres[(Q)*8+1],               \
                                     rres[(Q)*8+2], rres[(Q)*8+3]);              \
    *(float4*)(dp + 4) = make_float4(rres[(Q)*8+4], rres[(Q)*8+5],               \
                                     rres[(Q)*8+6], rres[(Q)*8+7]);              \
  }

  // stage residual d-chunk for chunk index dcn (d-range dcn*8..+7) into parity par
  auto write_lsr = [&](int dcn, int par) {
    if ((tid & 7) == (dcn >> 3)) {
      switch (dcn & 7) {
        case 0: WRQ(par, 0); break;
        case 1: WRQ(par, 1); break;
        case 2: WRQ(par, 2); break;
        case 3: WRQ(par, 3); break;
        case 4: WRQ(par, 4); break;
        case 5: WRQ(par, 5); break;
        case 6: WRQ(par, 6); break;
        case 7: WRQ(par, 7); break;
      }
    }
  };

  // prologue
  issue_chunk(0, 0, 0);
  write_lsr(0, 0);

  for (int l = 0; l < LLEV; ++l) {
    // ---- r_sq, exact round-1 summation order ----
    {
      float p = 0.f;
#pragma unroll
      for (int i = 0; i < 64; ++i) p = fmaf(rres[i], rres[i], p);
      ls_rsqp[own_row * 8 + (tid & 7)] = p;
    }
    __syncthreads();
    if (tid < ROWS) {
      float s = 0.f;
#pragma unroll
      for (int i = 0; i < 8; ++i) s += ls_rsqp[tid * 8 + i];
      ls_rsq[tid] = s;
    }
    __syncthreads();
    float rsqv[8];
#pragma unroll
    for (int r = 0; r < 8; ++r) rsqv[r] = ls_rsq[rg * 8 + r];

    float mv[8]; int mi[8];
#pragma unroll
    for (int r = 0; r < 8; ++r) { mv[r] = 3.4e38f; mi[r] = 0; }

    float acc[8][8];
    float4 cs0, cs1;

    for (int j = 0; j < 128; ++j) {
      const int kt  = j >> 6;
      const int buf = j & 1;

      __syncthreads();  // chunk j LDS ready; buf^1 free for DMA

      if ((j & 63) == 0) {
        cs0 = *(const float4*)(csq + l * KCODES + kt * KT + 4 * kg);
        cs1 = *(const float4*)(csq + l * KCODES + kt * KT + 256 + 4 * kg);
#pragma unroll
        for (int r = 0; r < 8; ++r)
#pragma unroll
          for (int c = 0; c < 8; ++c) acc[r][c] = 0.f;
      }

      // issue next chunk's DMA (cb only -> independent of compute)
      if (!(l == LLEV - 1 && j == 127)) {
        int nl = (j == 127) ? l + 1 : l;
        int nj = (j == 127) ? 0 : j + 1;
        issue_chunk(nl, nj, buf ^ 1);
      }
      if (j < 127) write_lsr((j + 1) & 63, (j + 1) & 1);

      // ---- compute chunk j: 8 d's, 8 rows x 8 cols per thread ----
      const float* cbb = &ls_cb[buf][0];
      const float* rb  = &ls_r[buf][0];
#pragma unroll
      for (int ds4 = 0; ds4 < 2; ++ds4) {
        float rvf[4][8];
#pragma unroll
        for (int r = 0; r < 8; ++r) {
          float4 t = *(const float4*)&rb[(rg * 8 + r) * 12 + ds4 * 4];
          rvf[0][r] = t.x; rvf[1][r] = t.y; rvf[2][r] = t.z; rvf[3][r] = t.w;
        }
#pragma unroll
        for (int jj = 0; jj < 4; ++jj) {
          float4 cv0 = *(const float4*)&cbb[(ds4 * 4 + jj) * KT + 4 * kg];
          float4 cv1 = *(const float4*)&cbb[(ds4 * 4 + jj) * KT + 256 + 4 * kg];
#pragma unroll
          for (int r = 0; r < 8; ++r) {
            float rv = rvf[jj][r];
            acc[r][0] = fmaf(rv, cv0.x, acc[r][0]);
            acc[r][1] = fmaf(rv, cv0.y, acc[r][1]);
            acc[r][2] = fmaf(rv, cv0.z, acc[r][2]);
            acc[r][3] = fmaf(rv, cv0.w, acc[r][3]);
            acc[r][4] = fmaf(rv, cv1.x, acc[r][4]);
            acc[r][5] = fmaf(rv, cv1.y, acc[r][5]);
            acc[r][6] = fmaf(rv, cv1.z, acc[r][6]);
            acc[r][7] = fmaf(rv, cv1.w, acc[r][7]);
          }
        }
      }

      // ---- merge scores into running argmin at end of each k-tile ----
      if ((j & 63) == 63) {
#pragma unroll
        for (int g = 0; g < 2; ++g) {
          float4 cs = g ? cs1 : cs0;
#pragma unroll
          for (int c = 0; c < 4; ++c) {
            int k = kt * KT + g * 256 + 4 * kg + c;
            float csv = (c == 0) ? cs.x : (c == 1) ? cs.y : (c == 2) ? cs.z : cs.w;
#pragma unroll
            for (int r = 0; r < 8; ++r) {
              float s = (rsqv[r] + csv) - 2.0f * acc[r][g * 4 + c];
              if (s < mv[r]) { mv[r] = s; mi[r] = k; }
            }
          }
        }
      }
    }

    // ---- in-wave argmin butterfly (value, then lowest index) ----
#pragma unroll
    for (int r = 0; r < 8; ++r) {
      float v = mv[r]; int i = mi[r];
#pragma unroll
      for (int off = 32; off > 0; off >>= 1) {
        float ov = __shfl_xor(v, off, 64);
        int   oi = __shfl_xor(i, off, 64);
        if (ov < v || (ov == v && oi < i)) { v = ov; i = oi; }
      }
      mv[r] = v; mi[r] = i;
      if (kg == r)
        out[CODES_OFF + (size_t)(rowbase + rg * 8 + r) * LLEV + l] = (float)i;
    }

    // ---- residual update: r -= cb[l][idx] ----
    {
      int r8 = (tid >> 3) & 7;
      int idx = mi[0];
#pragma unroll
      for (int r = 1; r < 8; ++r) if (r8 == r) idx = mi[r];
      const float4* cp = (const float4*)(cb + ((size_t)l * KCODES + idx) * DDIM + own_d0);
#pragma unroll
      for (int i = 0; i < 16; ++i) {
        float4 v = cp[i];
        rres[4*i]   -= v.x; rres[4*i+1] -= v.y;
        rres[4*i+2] -= v.z; rres[4*i+3] -= v.w;
      }
    }
    // stage chunk0 of next level from updated residual
    if (l < LLEV - 1) write_lsr(0, 0);
  }

  // ---- quant = input - residual_final ----
  {
    const float4* xp = (const float4*)(x + (size_t)(rowbase + own_row) * DDIM + own_d0);
    float4* op = (float4*)(out + (size_t)(rowbase + own_row) * DDIM + own_d0);
#pragma unroll
    for (int i = 0; i < 16; ++i) {
      float4 v = xp[i];
      op[i] = make_float4(v.x - rres[4*i],   v.y - rres[4*i+1],
                          v.z - rres[4*i+2], v.w - rres[4*i+3]);
    }
  }
}

// ---------------- fallback (round-1 kernel, used if ws too small) ----------------
#define DC 16
#define RSTRIDE 20

__launch_bounds__(256, 2)
__global__ void rq_kernel(const float* __restrict__ x, const float* __restrict__ cb,
                          const float* __restrict__ csq, float* __restrict__ out) {
  __shared__ float ls_cbT[DC * KT];
  __shared__ float ls_r[ROWS * RSTRIDE];
  __shared__ float ls_minv[ROWS * 64];
  __shared__ int   ls_mini[ROWS * 64];
  __shared__ float ls_rsqp[ROWS * 8];
  __shared__ float ls_rsq[ROWS];
  __shared__ int   ls_idx[ROWS];

  const int tid = threadIdx.x;
  const int rg  = tid >> 6;
  const int kg  = tid & 63;
  const int own_row = tid >> 3;
  const int own_d0  = (tid & 7) * 64;
  const int rowbase = blockIdx.x * ROWS;

  float rres[64];
  {
    const float4* xp = (const float4*)(x + (size_t)(rowbase + own_row) * DDIM + own_d0);
#pragma unroll
    for (int i = 0; i < 16; ++i) {
      float4 v = xp[i];
      rres[4*i] = v.x; rres[4*i+1] = v.y; rres[4*i+2] = v.z; rres[4*i+3] = v.w;
    }
  }

  for (int l = 0; l < LLEV; ++l) {
    {
      float p = 0.f;
#pragma unroll
      for (int i = 0; i < 64; ++i) p = fmaf(rres[i], rres[i], p);
      ls_rsqp[own_row * 8 + (tid & 7)] = p;
    }
    __syncthreads();
    if (tid < ROWS) {
      float s = 0.f;
#pragma unroll
      for (int i = 0; i < 8; ++i) s += ls_rsqp[tid * 8 + i];
      ls_rsq[tid] = s;
    }

    float mv[8]; int mi[8];
#pragma unroll
    for (int r = 0; r < 8; ++r) { mv[r] = 3.4e38f; mi[r] = 0; }

    const float* cbl = cb + (size_t)l * KCODES * DDIM;

    for (int kt = 0; kt < KCODES / KT; ++kt) {
      float acc[8][8];
#pragma unroll
      for (int r = 0; r < 8; ++r)
#pragma unroll
        for (int c = 0; c < 8; ++c) acc[r][c] = 0.f;

      for (int dc = 0; dc < DDIM / DC; ++dc) {
        __syncthreads();
        {
          int krow = tid >> 2;
          int dcol = (tid & 3) * 4;
#pragma unroll
          for (int p = 0; p < 8; ++p) {
            int klocal = p * 64 + krow;
            float4 v = *(const float4*)(cbl + (size_t)(kt * KT + klocal) * DDIM + dc * DC + dcol);
            ls_cbT[(dcol + 0) * KT + klocal] = v.x;
            ls_cbT[(dcol + 1) * KT + klocal] = v.y;
            ls_cbT[(dcol + 2) * KT + klocal] = v.z;
            ls_cbT[(dcol + 3) * KT + klocal] = v.w;
          }
        }
        if ((tid & 7) == (dc >> 2)) {
          switch (dc & 3) {
            case 0:
#pragma unroll
              for (int i = 0; i < 4; ++i)
                *(float4*)&ls_r[own_row * RSTRIDE + i * 4] =
                  make_float4(rres[0*16+4*i], rres[0*16+4*i+1], rres[0*16+4*i+2], rres[0*16+4*i+3]);
              break;
            case 1:
#pragma unroll
              for (int i = 0; i < 4; ++i)
                *(float4*)&ls_r[own_row * RSTRIDE + i * 4] =
                  make_float4(rres[1*16+4*i], rres[1*16+4*i+1], rres[1*16+4*i+2], rres[1*16+4*i+3]);
              break;
            case 2:
#pragma unroll
              for (int i = 0; i < 4; ++i)
                *(float4*)&ls_r[own_row * RSTRIDE + i * 4] =
                  make_float4(rres[2*16+4*i], rres[2*16+4*i+1], rres[2*16+4*i+2], rres[2*16+4*i+3]);
              break;
            default:
#pragma unroll
              for (int i = 0; i < 4; ++i)
                *(float4*)&ls_r[own_row * RSTRIDE + i * 4] =
                  make_float4(rres[3*16+4*i], rres[3*16+4*i+1], rres[3*16+4*i+2], rres[3*16+4*i+3]);
              break;
          }
        }
        __syncthreads();
        for (int ds4 = 0; ds4 < DC / 4; ++ds4) {
          float rvf[4][8];
#pragma unroll
          for (int r = 0; r < 8; ++r) {
            float4 t = *(const float4*)&ls_r[(rg * 8 + r) * RSTRIDE + ds4 * 4];
            rvf[0][r] = t.x; rvf[1][r] = t.y; rvf[2][r] = t.z; rvf[3][r] = t.w;
          }
#pragma unroll
          for (int jj = 0; jj < 4; ++jj) {
            float4 cv0 = *(const float4*)&ls_cbT[(ds4 * 4 + jj) * KT + 4 * kg];
            float4 cv1 = *(const float4*)&ls_cbT[(ds4 * 4 + jj) * KT + KT / 2 + 4 * kg];
#pragma unroll
            for (int r = 0; r < 8; ++r) {
              float rv = rvf[jj][r];
              acc[r][0] = fmaf(rv, cv0.x, acc[r][0]);
              acc[r][1] = fmaf(rv, cv0.y, acc[r][1]);
              acc[r][2] = fmaf(rv, cv0.z, acc[r][2]);
              acc[r][3] = fmaf(rv, cv0.w, acc[r][3]);
              acc[r][4] = fmaf(rv, cv1.x, acc[r][4]);
              acc[r][5] = fmaf(rv, cv1.y, acc[r][5]);
              acc[r][6] = fmaf(rv, cv1.z, acc[r][6]);
              acc[r][7] = fmaf(rv, cv1.w, acc[r][7]);
            }
          }
        }
      }
#pragma unroll
      for (int g = 0; g < 2; ++g)
#pragma unroll
        for (int c = 0; c < 4; ++c) {
          int k = kt * KT + g * (KT / 2) + 4 * kg + c;
          float cs = csq[l * KCODES + k];
#pragma unroll
          for (int r = 0; r < 8; ++r) {
            float s = (ls_rsq[rg * 8 + r] + cs) - 2.0f * acc[r][g * 4 + c];
            if (s < mv[r]) { mv[r] = s; mi[r] = k; }
          }
        }
    }

#pragma unroll
    for (int r = 0; r < 8; ++r) {
      ls_minv[(rg * 8 + r) * 64 + kg] = mv[r];
      ls_mini[(rg * 8 + r) * 64 + kg] = mi[r];
    }
    __syncthreads();
    if (tid < ROWS) {
      float bv = ls_minv[tid * 64]; int bi = ls_mini[tid * 64];
      for (int i = 1; i < 64; ++i) {
        float v = ls_minv[tid * 64 + i]; int ii = ls_mini[tid * 64 + i];
        if (v < bv || (v == bv && ii < bi)) { bv = v; bi = ii; }
      }
      ls_idx[tid] = bi;
      out[CODES_OFF + (size_t)(rowbase + tid) * LLEV + l] = (float)bi;
    }
    __syncthreads();
    {
      int idx = ls_idx[own_row];
      const float4* cp = (const float4*)(cbl + (size_t)idx * DDIM + own_d0);
#pragma unroll
      for (int i = 0; i < 16; ++i) {
        float4 v = cp[i];
        rres[4*i]   -= v.x; rres[4*i+1] -= v.y;
        rres[4*i+2] -= v.z; rres[4*i+3] -= v.w;
      }
    }
  }

  {
    const float4* xp = (const float4*)(x + (size_t)(rowbase + own_row) * DDIM + own_d0);
    float4* op = (float4*)(out + (size_t)(rowbase + own_row) * DDIM + own_d0);
#pragma unroll
    for (int i = 0; i < 16; ++i) {
      float4 v = xp[i];
      op[i] = make_float4(v.x - rres[4*i],   v.y - rres[4*i+1],
                          v.z - rres[4*i+2], v.w - rres[4*i+3]);
    }
  }
}

extern "C" void kernel_launch(void* const* d_in, const int* in_sizes, int n_in,
                              void* d_out, int out_size, void* d_ws, size_t ws_size,
                              hipStream_t stream) {
  const float* x  = (const float*)d_in[0];
  const float* cb = (const float*)d_in[1];
  float* out = (float*)d_out;
  float* csq = (float*)d_ws;                 // [L*K]
  float* cbT = (float*)d_ws + 4096;          // [L][D][K]

  const size_t need = (size_t)(4096 + LLEV * DDIM * KCODES) * sizeof(float);

  csq_kernel<<<dim3((LLEV * KCODES) / 4), dim3(256), 0, stream>>>(cb, csq);
  if (ws_size >= need) {
    transpose_kernel<<<dim3(KCODES / 64, DDIM / 64, LLEV), dim3(256), 0, stream>>>(cb, cbT);
    rq_fast<<<dim3(NROWS_TOTAL / ROWS), dim3(256), 0, stream>>>(x, cb, csq, cbT, out);
  } else {
    rq_kernel<<<dim3(NROWS_TOTAL / ROWS), dim3(256), 0, stream>>>(x, cb, csq, out);
  }
}